// Round 1
// baseline (1666.224 us; speedup 1.0000x reference)
//
#include <hip/hip_runtime.h>
#include <cstdint>
#include <cstddef>

// ---- problem constants (DeepSeek-V3 MoE config) ----
#define T_TOK 1024
#define H_DIM 1024
#define I_DIM 704
#define E_NUM 64
#define TOPK 8
#define NGRP 8
#define GSIZE 8          // E_NUM / NGRP
#define TOPKG 4
#define SI_DIM 1408
#define RSCALE 2.5f
#define NSLOT (T_TOK * TOPK)   // 8192

// GEMM tiling
#define KC 32
#define MT 128
#define NT 64

// ---------------- routing ----------------
__global__ __launch_bounds__(64) void route_kernel(
    const float* __restrict__ x, const float* __restrict__ gw, const float* __restrict__ gb,
    int* __restrict__ counts, int* __restrict__ tk_idx, float* __restrict__ tk_w)
{
    const int t = blockIdx.x;
    __shared__ float xs[H_DIM];
    __shared__ float raw[E_NUM];
    __shared__ float sc[E_NUM];
    __shared__ float masked[E_NUM];
    __shared__ float gsc[NGRP];
    const int tid = threadIdx.x;

    const float4* xrow = (const float4*)(x + (size_t)t * H_DIM);
    for (int i = tid; i < H_DIM / 4; i += 64) ((float4*)xs)[i] = xrow[i];
    __syncthreads();

    float a = 0.f;
    const float* w = gw + (size_t)tid * H_DIM;
    for (int h = 0; h < H_DIM; h += 4) {
        float4 w4 = *(const float4*)(w + h);
        a += xs[h] * w4.x + xs[h+1] * w4.y + xs[h+2] * w4.z + xs[h+3] * w4.w;
    }
    float s = 1.f / (1.f + expf(-a));
    raw[tid] = s;
    sc[tid] = s + gb[tid];
    __syncthreads();

    if (tid == 0) {
        // group scores = sum of top-2 scores_for_choice within each group
        for (int g = 0; g < NGRP; ++g) {
            float m1 = -1e30f, m2 = -1e30f;
            for (int j = 0; j < GSIZE; ++j) {
                float v = sc[g * GSIZE + j];
                if (v > m1) { m2 = m1; m1 = v; }
                else if (v > m2) { m2 = v; }
            }
            gsc[g] = m1 + m2;
        }
        // top-4 groups (stable: strict > keeps lowest index on ties)
        bool gsel[NGRP];
        for (int g = 0; g < NGRP; ++g) gsel[g] = false;
        for (int k = 0; k < TOPKG; ++k) {
            int best = -1; float bv = -1e30f;
            for (int g = 0; g < NGRP; ++g)
                if (!gsel[g] && gsc[g] > bv) { bv = gsc[g]; best = g; }
            gsel[best] = true;
        }
        for (int e = 0; e < E_NUM; ++e)
            masked[e] = gsel[e / GSIZE] ? sc[e] : 0.0f;
        // top-8 experts from masked biased scores; weights from UNbiased scores
        int idx[TOPK];
        float wsum = 0.f;
        for (int k = 0; k < TOPK; ++k) {
            int best = 0; float bv = -1e30f;
            for (int e = 0; e < E_NUM; ++e)
                if (masked[e] > bv) { bv = masked[e]; best = e; }
            masked[best] = -1e30f;
            idx[k] = best;
            wsum += raw[best];
        }
        float inv = RSCALE / (wsum + 1e-20f);
        for (int k = 0; k < TOPK; ++k) {
            tk_idx[t * TOPK + k] = idx[k];
            tk_w[t * TOPK + k] = raw[idx[k]] * inv;
            atomicAdd(&counts[idx[k]], 1);
        }
    }
}

__global__ void zero_kernel(int* counts, int* fillc)
{
    int i = threadIdx.x;
    if (i < E_NUM) { counts[i] = 0; fillc[i] = 0; }
}

__global__ void scan_kernel(const int* __restrict__ counts, int* __restrict__ offs)
{
    if (threadIdx.x == 0) {
        int acc = 0;
        for (int e = 0; e < E_NUM; ++e) { offs[e] = acc; acc += counts[e]; }
    }
}

__global__ void fill_kernel(const int* __restrict__ tk_idx, const float* __restrict__ tk_w,
                            const int* __restrict__ offs, int* __restrict__ fillc,
                            int* __restrict__ tok_list, float* __restrict__ w_list)
{
    int t = blockIdx.x * blockDim.x + threadIdx.x;
    if (t >= T_TOK) return;
    for (int k = 0; k < TOPK; ++k) {
        int e = tk_idx[t * TOPK + k];
        int pos = offs[e] + atomicAdd(&fillc[e], 1);
        tok_list[pos] = t;
        w_list[pos] = tk_w[t * TOPK + k];
    }
}

// ---------------- routed gate/up (gathered GEMM, SwiGLU fused) ----------------
__global__ __launch_bounds__(256) void gateup_routed(
    const float* __restrict__ x, const float* __restrict__ Wg, const float* __restrict__ Wu,
    const int* __restrict__ offs, const int* __restrict__ counts,
    const int* __restrict__ tok_list, float* __restrict__ act)
{
    const int e = blockIdx.z;
    const int cnt = counts[e];
    const int m0 = blockIdx.y * MT;
    if (m0 >= cnt) return;
    const int off = offs[e];
    const int n0 = blockIdx.x * NT;

    __shared__ float xs[KC][MT + 4];
    __shared__ float gs[KC][NT + 4];
    __shared__ float us[KC][NT + 4];
    __shared__ int toks[MT];

    const int tid = threadIdx.x;
    if (tid < MT) toks[tid] = (m0 + tid < cnt) ? tok_list[off + m0 + tid] : -1;
    __syncthreads();

    const int tx = tid & 15;   // 16 n-groups of 4
    const int ty = tid >> 4;   // 16 m-groups of 8

    float ag[8][4] = {{0.f}};
    float au[8][4] = {{0.f}};

    const float* wgp = Wg + (size_t)e * I_DIM * H_DIM + (size_t)n0 * H_DIM;
    const float* wup = Wu + (size_t)e * I_DIM * H_DIM + (size_t)n0 * H_DIM;

    for (int k0 = 0; k0 < H_DIM; k0 += KC) {
        #pragma unroll
        for (int j = 0; j < 4; ++j) {
            int idx = tid + j * 256;
            int r = idx >> 3, c = (idx & 7) * 4;
            float4 v = make_float4(0.f, 0.f, 0.f, 0.f);
            int tkn = toks[r];
            if (tkn >= 0) v = *(const float4*)(x + (size_t)tkn * H_DIM + k0 + c);
            xs[c][r] = v.x; xs[c+1][r] = v.y; xs[c+2][r] = v.z; xs[c+3][r] = v.w;
        }
        #pragma unroll
        for (int j = 0; j < 2; ++j) {
            int idx = tid + j * 256;
            int r = idx >> 3, c = (idx & 7) * 4;
            float4 g = *(const float4*)(wgp + (size_t)r * H_DIM + k0 + c);
            gs[c][r] = g.x; gs[c+1][r] = g.y; gs[c+2][r] = g.z; gs[c+3][r] = g.w;
            float4 u = *(const float4*)(wup + (size_t)r * H_DIM + k0 + c);
            us[c][r] = u.x; us[c+1][r] = u.y; us[c+2][r] = u.z; us[c+3][r] = u.w;
        }
        __syncthreads();
        #pragma unroll 4
        for (int k = 0; k < KC; ++k) {
            float4 xlo = *(const float4*)&xs[k][ty * 8];
            float4 xhi = *(const float4*)&xs[k][ty * 8 + 4];
            float4 g4 = *(const float4*)&gs[k][tx * 4];
            float4 u4 = *(const float4*)&us[k][tx * 4];
            float xv[8] = {xlo.x, xlo.y, xlo.z, xlo.w, xhi.x, xhi.y, xhi.z, xhi.w};
            float gv[4] = {g4.x, g4.y, g4.z, g4.w};
            float uv[4] = {u4.x, u4.y, u4.z, u4.w};
            #pragma unroll
            for (int jm = 0; jm < 8; ++jm)
                #pragma unroll
                for (int jn = 0; jn < 4; ++jn) {
                    ag[jm][jn] += xv[jm] * gv[jn];
                    au[jm][jn] += xv[jm] * uv[jn];
                }
        }
        __syncthreads();
    }

    #pragma unroll
    for (int jm = 0; jm < 8; ++jm) {
        int s = m0 + ty * 8 + jm;
        if (s >= cnt) continue;
        float* ap = act + (size_t)(off + s) * I_DIM + n0 + tx * 4;
        #pragma unroll
        for (int jn = 0; jn < 4; ++jn) {
            float g = ag[jm][jn];
            ap[jn] = g / (1.f + __expf(-g)) * au[jm][jn];
        }
    }
}

// ---------------- routed down proj (gathered GEMM, atomic scatter-add) ----------------
__global__ __launch_bounds__(256) void down_routed(
    const float* __restrict__ act, const float* __restrict__ Wd,
    const int* __restrict__ offs, const int* __restrict__ counts,
    const int* __restrict__ tok_list, const float* __restrict__ w_list,
    float* __restrict__ out)
{
    const int e = blockIdx.z;
    const int cnt = counts[e];
    const int m0 = blockIdx.y * MT;
    if (m0 >= cnt) return;
    const int off = offs[e];
    const int n0 = blockIdx.x * NT;

    __shared__ float as_[KC][MT + 4];
    __shared__ float ws_[KC][NT + 4];

    const int tid = threadIdx.x;
    const int tx = tid & 15, ty = tid >> 4;
    float acc[8][4] = {{0.f}};

    const float* wdp = Wd + (size_t)e * H_DIM * I_DIM + (size_t)n0 * I_DIM;
    const float* ap = act + (size_t)(off + m0) * I_DIM;
    const int rows = cnt - m0;

    for (int k0 = 0; k0 < I_DIM; k0 += KC) {
        #pragma unroll
        for (int j = 0; j < 4; ++j) {
            int idx = tid + j * 256;
            int r = idx >> 3, c = (idx & 7) * 4;
            float4 v = make_float4(0.f, 0.f, 0.f, 0.f);
            if (r < rows) v = *(const float4*)(ap + (size_t)r * I_DIM + k0 + c);
            as_[c][r] = v.x; as_[c+1][r] = v.y; as_[c+2][r] = v.z; as_[c+3][r] = v.w;
        }
        #pragma unroll
        for (int j = 0; j < 2; ++j) {
            int idx = tid + j * 256;
            int r = idx >> 3, c = (idx & 7) * 4;
            float4 w4 = *(const float4*)(wdp + (size_t)r * I_DIM + k0 + c);
            ws_[c][r] = w4.x; ws_[c+1][r] = w4.y; ws_[c+2][r] = w4.z; ws_[c+3][r] = w4.w;
        }
        __syncthreads();
        #pragma unroll 4
        for (int k = 0; k < KC; ++k) {
            float4 alo = *(const float4*)&as_[k][ty * 8];
            float4 ahi = *(const float4*)&as_[k][ty * 8 + 4];
            float4 w4 = *(const float4*)&ws_[k][tx * 4];
            float av[8] = {alo.x, alo.y, alo.z, alo.w, ahi.x, ahi.y, ahi.z, ahi.w};
            float wv[4] = {w4.x, w4.y, w4.z, w4.w};
            #pragma unroll
            for (int jm = 0; jm < 8; ++jm)
                #pragma unroll
                for (int jn = 0; jn < 4; ++jn)
                    acc[jm][jn] += av[jm] * wv[jn];
        }
        __syncthreads();
    }

    #pragma unroll
    for (int jm = 0; jm < 8; ++jm) {
        int s = m0 + ty * 8 + jm;
        if (s >= cnt) continue;
        int t = tok_list[off + s];
        float w = w_list[off + s];
        float* op = out + (size_t)t * H_DIM + n0 + tx * 4;
        #pragma unroll
        for (int jn = 0; jn < 4; ++jn)
            atomicAdd(&op[jn], w * acc[jm][jn]);
    }
}

// ---------------- shared expert gate/up (dense GEMM, SwiGLU fused) ----------------
__global__ __launch_bounds__(256) void gateup_shared(
    const float* __restrict__ x, const float* __restrict__ Sg, const float* __restrict__ Su,
    float* __restrict__ sact)
{
    const int m0 = blockIdx.y * MT;
    const int n0 = blockIdx.x * NT;

    __shared__ float xs[KC][MT + 4];
    __shared__ float gs[KC][NT + 4];
    __shared__ float us[KC][NT + 4];

    const int tid = threadIdx.x;
    const int tx = tid & 15, ty = tid >> 4;
    float ag[8][4] = {{0.f}};
    float au[8][4] = {{0.f}};

    const float* gp = Sg + (size_t)n0 * H_DIM;
    const float* up = Su + (size_t)n0 * H_DIM;

    for (int k0 = 0; k0 < H_DIM; k0 += KC) {
        #pragma unroll
        for (int j = 0; j < 4; ++j) {
            int idx = tid + j * 256;
            int r = idx >> 3, c = (idx & 7) * 4;
            float4 v = *(const float4*)(x + (size_t)(m0 + r) * H_DIM + k0 + c);
            xs[c][r] = v.x; xs[c+1][r] = v.y; xs[c+2][r] = v.z; xs[c+3][r] = v.w;
        }
        #pragma unroll
        for (int j = 0; j < 2; ++j) {
            int idx = tid + j * 256;
            int r = idx >> 3, c = (idx & 7) * 4;
            float4 g = *(const float4*)(gp + (size_t)r * H_DIM + k0 + c);
            gs[c][r] = g.x; gs[c+1][r] = g.y; gs[c+2][r] = g.z; gs[c+3][r] = g.w;
            float4 u = *(const float4*)(up + (size_t)r * H_DIM + k0 + c);
            us[c][r] = u.x; us[c+1][r] = u.y; us[c+2][r] = u.z; us[c+3][r] = u.w;
        }
        __syncthreads();
        #pragma unroll 4
        for (int k = 0; k < KC; ++k) {
            float4 xlo = *(const float4*)&xs[k][ty * 8];
            float4 xhi = *(const float4*)&xs[k][ty * 8 + 4];
            float4 g4 = *(const float4*)&gs[k][tx * 4];
            float4 u4 = *(const float4*)&us[k][tx * 4];
            float xv[8] = {xlo.x, xlo.y, xlo.z, xlo.w, xhi.x, xhi.y, xhi.z, xhi.w};
            float gv[4] = {g4.x, g4.y, g4.z, g4.w};
            float uv[4] = {u4.x, u4.y, u4.z, u4.w};
            #pragma unroll
            for (int jm = 0; jm < 8; ++jm)
                #pragma unroll
                for (int jn = 0; jn < 4; ++jn) {
                    ag[jm][jn] += xv[jm] * gv[jn];
                    au[jm][jn] += xv[jm] * uv[jn];
                }
        }
        __syncthreads();
    }

    #pragma unroll
    for (int jm = 0; jm < 8; ++jm) {
        int t = m0 + ty * 8 + jm;
        float* sp = sact + (size_t)t * SI_DIM + n0 + tx * 4;
        #pragma unroll
        for (int jn = 0; jn < 4; ++jn) {
            float g = ag[jm][jn];
            sp[jn] = g / (1.f + __expf(-g)) * au[jm][jn];
        }
    }
}

// ---------------- shared expert down proj (dense GEMM, writes out) ----------------
__global__ __launch_bounds__(256) void down_shared(
    const float* __restrict__ sact, const float* __restrict__ Sd,
    float* __restrict__ out)
{
    const int m0 = blockIdx.y * MT;
    const int n0 = blockIdx.x * NT;

    __shared__ float as_[KC][MT + 4];
    __shared__ float ws_[KC][NT + 4];

    const int tid = threadIdx.x;
    const int tx = tid & 15, ty = tid >> 4;
    float acc[8][4] = {{0.f}};

    const float* wp = Sd + (size_t)n0 * SI_DIM;

    for (int k0 = 0; k0 < SI_DIM; k0 += KC) {
        #pragma unroll
        for (int j = 0; j < 4; ++j) {
            int idx = tid + j * 256;
            int r = idx >> 3, c = (idx & 7) * 4;
            float4 v = *(const float4*)(sact + (size_t)(m0 + r) * SI_DIM + k0 + c);
            as_[c][r] = v.x; as_[c+1][r] = v.y; as_[c+2][r] = v.z; as_[c+3][r] = v.w;
        }
        #pragma unroll
        for (int j = 0; j < 2; ++j) {
            int idx = tid + j * 256;
            int r = idx >> 3, c = (idx & 7) * 4;
            float4 w4 = *(const float4*)(wp + (size_t)r * SI_DIM + k0 + c);
            ws_[c][r] = w4.x; ws_[c+1][r] = w4.y; ws_[c+2][r] = w4.z; ws_[c+3][r] = w4.w;
        }
        __syncthreads();
        #pragma unroll 4
        for (int k = 0; k < KC; ++k) {
            float4 alo = *(const float4*)&as_[k][ty * 8];
            float4 ahi = *(const float4*)&as_[k][ty * 8 + 4];
            float4 w4 = *(const float4*)&ws_[k][tx * 4];
            float av[8] = {alo.x, alo.y, alo.z, alo.w, ahi.x, ahi.y, ahi.z, ahi.w};
            float wv[4] = {w4.x, w4.y, w4.z, w4.w};
            #pragma unroll
            for (int jm = 0; jm < 8; ++jm)
                #pragma unroll
                for (int jn = 0; jn < 4; ++jn)
                    acc[jm][jn] += av[jm] * wv[jn];
        }
        __syncthreads();
    }

    #pragma unroll
    for (int jm = 0; jm < 8; ++jm) {
        int t = m0 + ty * 8 + jm;
        float* op = out + (size_t)t * H_DIM + n0 + tx * 4;
        #pragma unroll
        for (int jn = 0; jn < 4; ++jn)
            op[jn] = acc[jm][jn];
    }
}

// ---------------- launch ----------------
extern "C" void kernel_launch(void* const* d_in, const int* in_sizes, int n_in,
                              void* d_out, int out_size, void* d_ws, size_t ws_size,
                              hipStream_t stream)
{
    const float* x  = (const float*)d_in[0];
    const float* gw = (const float*)d_in[1];
    const float* gb = (const float*)d_in[2];
    const float* Wg = (const float*)d_in[3];
    const float* Wu = (const float*)d_in[4];
    const float* Wd = (const float*)d_in[5];
    const float* Sg = (const float*)d_in[6];
    const float* Su = (const float*)d_in[7];
    const float* Sd = (const float*)d_in[8];
    float* out = (float*)d_out;

    // workspace layout (all 4B types; act/sact 16B aligned by construction)
    int* counts   = (int*)d_ws;              // 64
    int* fillc    = counts + 64;             // 64
    int* offs     = fillc + 64;              // 64
    int* tk_idx   = offs + 64;               // 8192
    float* tk_w   = (float*)(tk_idx + NSLOT);// 8192
    int* tok_list = (int*)(tk_w + NSLOT);    // 8192
    float* w_list = (float*)(tok_list + NSLOT); // 8192
    float* act    = w_list + NSLOT;          // 8192*704
    float* sact   = act + (size_t)NSLOT * I_DIM; // 1024*1408

    zero_kernel<<<1, 64, 0, stream>>>(counts, fillc);
    route_kernel<<<T_TOK, 64, 0, stream>>>(x, gw, gb, counts, tk_idx, tk_w);
    scan_kernel<<<1, 64, 0, stream>>>(counts, offs);
    fill_kernel<<<4, 256, 0, stream>>>(tk_idx, tk_w, offs, fillc, tok_list, w_list);
    gateup_routed<<<dim3(11, 8, 64), 256, 0, stream>>>(x, Wg, Wu, offs, counts, tok_list, act);
    gateup_shared<<<dim3(22, 8, 1), 256, 0, stream>>>(x, Sg, Su, sact);
    down_shared<<<dim3(16, 8, 1), 256, 0, stream>>>(sact, Sd, out);
    down_routed<<<dim3(16, 8, 64), 256, 0, stream>>>(act, Wd, offs, counts, tok_list, w_list, out);
}

// Round 2
// 841.966 us; speedup vs baseline: 1.9790x; 1.9790x over previous
//
#include <hip/hip_runtime.h>
#include <hip/hip_bf16.h>
#include <cstdint>
#include <cstddef>

// ---- problem constants (DeepSeek-V3 MoE config) ----
#define T_TOK 1024
#define H_DIM 1024
#define I_DIM 704
#define E_NUM 64
#define TOPK 8
#define NGRP 8
#define GSIZE 8          // E_NUM / NGRP
#define TOPKG 4
#define SI_DIM 1408
#define RSCALE 2.5f
#define NSLOT (T_TOK * TOPK)   // 8192

#define AP 72            // LDS row pitch in bf16 elems (64 + 8 pad -> 144B rows, 2-way max bank aliasing)

typedef short bf16x8 __attribute__((ext_vector_type(8)));
typedef float f32x4 __attribute__((ext_vector_type(4)));

__device__ inline unsigned pk2(float x, float y) {
    __hip_bfloat162 h2 = __float22bfloat162_rn(make_float2(x, y));
    unsigned u; __builtin_memcpy(&u, &h2, 4); return u;
}
__device__ inline unsigned short bf1(float x) {
    __hip_bfloat16 h = __float2bfloat16(x);
    unsigned short u; __builtin_memcpy(&u, &h, 2); return u;
}

// ---------------- routing ----------------
__global__ __launch_bounds__(64) void route_kernel(
    const float* __restrict__ x, const float* __restrict__ gw, const float* __restrict__ gb,
    int* __restrict__ counts, int* __restrict__ tk_idx, float* __restrict__ tk_w)
{
    const int t = blockIdx.x;
    __shared__ float xs[H_DIM];
    __shared__ float raw[E_NUM];
    __shared__ float sc[E_NUM];
    __shared__ float masked[E_NUM];
    __shared__ float gsc[NGRP];
    const int tid = threadIdx.x;

    const float4* xrow = (const float4*)(x + (size_t)t * H_DIM);
    for (int i = tid; i < H_DIM / 4; i += 64) ((float4*)xs)[i] = xrow[i];
    __syncthreads();

    float a = 0.f;
    const float* w = gw + (size_t)tid * H_DIM;
    for (int h = 0; h < H_DIM; h += 4) {
        float4 w4 = *(const float4*)(w + h);
        a += xs[h] * w4.x + xs[h+1] * w4.y + xs[h+2] * w4.z + xs[h+3] * w4.w;
    }
    float s = 1.f / (1.f + expf(-a));
    raw[tid] = s;
    sc[tid] = s + gb[tid];
    __syncthreads();

    if (tid == 0) {
        for (int g = 0; g < NGRP; ++g) {
            float m1 = -1e30f, m2 = -1e30f;
            for (int j = 0; j < GSIZE; ++j) {
                float v = sc[g * GSIZE + j];
                if (v > m1) { m2 = m1; m1 = v; }
                else if (v > m2) { m2 = v; }
            }
            gsc[g] = m1 + m2;
        }
        bool gsel[NGRP];
        for (int g = 0; g < NGRP; ++g) gsel[g] = false;
        for (int k = 0; k < TOPKG; ++k) {
            int best = -1; float bv = -1e30f;
            for (int g = 0; g < NGRP; ++g)
                if (!gsel[g] && gsc[g] > bv) { bv = gsc[g]; best = g; }
            gsel[best] = true;
        }
        for (int e = 0; e < E_NUM; ++e)
            masked[e] = gsel[e / GSIZE] ? sc[e] : 0.0f;
        int idx[TOPK];
        float wsum = 0.f;
        for (int k = 0; k < TOPK; ++k) {
            int best = 0; float bv = -1e30f;
            for (int e = 0; e < E_NUM; ++e)
                if (masked[e] > bv) { bv = masked[e]; best = e; }
            masked[best] = -1e30f;
            idx[k] = best;
            wsum += raw[best];
        }
        float inv = RSCALE / (wsum + 1e-20f);
        for (int k = 0; k < TOPK; ++k) {
            tk_idx[t * TOPK + k] = idx[k];
            tk_w[t * TOPK + k] = raw[idx[k]] * inv;
            atomicAdd(&counts[idx[k]], 1);
        }
    }
}

__global__ void zero_kernel(int* counts, int* fillc)
{
    int i = threadIdx.x;
    if (i < E_NUM) { counts[i] = 0; fillc[i] = 0; }
}

__global__ void scan_kernel(const int* __restrict__ counts, int* __restrict__ offs)
{
    if (threadIdx.x == 0) {
        int acc = 0;
        for (int e = 0; e < E_NUM; ++e) { offs[e] = acc; acc += counts[e]; }
    }
}

__global__ void fill_kernel(const int* __restrict__ tk_idx, const float* __restrict__ tk_w,
                            const int* __restrict__ offs, int* __restrict__ fillc,
                            int* __restrict__ tok_list, float* __restrict__ w_list)
{
    int t = blockIdx.x * blockDim.x + threadIdx.x;
    if (t >= T_TOK) return;
    for (int k = 0; k < TOPK; ++k) {
        int e = tk_idx[t * TOPK + k];
        int pos = offs[e] + atomicAdd(&fillc[e], 1);
        tok_list[pos] = t;
        w_list[pos] = tk_w[t * TOPK + k];
    }
}

// ---------------- routed gate/up: MFMA, SwiGLU + combine-weight fused, bf16 act out ----------------
__global__ __launch_bounds__(256) void gateup_routed_mfma(
    const float* __restrict__ x, const float* __restrict__ Wg, const float* __restrict__ Wu,
    const int* __restrict__ offs, const int* __restrict__ counts,
    const int* __restrict__ tok_list, const float* __restrict__ w_list,
    unsigned short* __restrict__ act)
{
    const int e = blockIdx.z;
    const int cnt = counts[e];
    const int m0 = blockIdx.y * 128;
    if (m0 >= cnt) return;
    const int off = offs[e];
    const int n0 = blockIdx.x * 64;

    __shared__ unsigned short As[128 * AP];
    __shared__ unsigned short Bg[64 * AP];
    __shared__ unsigned short Bu[64 * AP];
    __shared__ int toks[128];
    __shared__ float wts[128];

    const int tid = threadIdx.x;
    if (tid < 128) {
        int s = m0 + tid;
        toks[tid] = (s < cnt) ? tok_list[off + s] : -1;
        wts[tid]  = (s < cnt) ? w_list[off + s] : 0.f;
    }
    __syncthreads();

    const int lane = tid & 63;
    const int wv = tid >> 6;
    const int lr = lane & 15;
    const int lq = lane >> 4;

    f32x4 accg[2][4], accu[2][4];
    #pragma unroll
    for (int i = 0; i < 2; ++i)
        #pragma unroll
        for (int j = 0; j < 4; ++j) {
            accg[i][j] = (f32x4){0.f, 0.f, 0.f, 0.f};
            accu[i][j] = (f32x4){0.f, 0.f, 0.f, 0.f};
        }

    const float* wgp = Wg + (size_t)e * I_DIM * H_DIM + (size_t)n0 * H_DIM;
    const float* wup = Wu + (size_t)e * I_DIM * H_DIM + (size_t)n0 * H_DIM;

    const int ar = tid >> 4;          // 0..15
    const int ac = (tid & 15) * 4;    // 0..60

    for (int k0 = 0; k0 < H_DIM; k0 += 64) {
        #pragma unroll
        for (int p = 0; p < 8; ++p) {
            int r = ar + p * 16;
            int tkn = toks[r];
            float4 v = make_float4(0.f, 0.f, 0.f, 0.f);
            if (tkn >= 0) v = *(const float4*)(x + (size_t)tkn * H_DIM + k0 + ac);
            *(uint2*)&As[r * AP + ac] = make_uint2(pk2(v.x, v.y), pk2(v.z, v.w));
        }
        #pragma unroll
        for (int p = 0; p < 4; ++p) {
            int r = ar + p * 16;
            float4 g = *(const float4*)(wgp + (size_t)r * H_DIM + k0 + ac);
            *(uint2*)&Bg[r * AP + ac] = make_uint2(pk2(g.x, g.y), pk2(g.z, g.w));
            float4 u = *(const float4*)(wup + (size_t)r * H_DIM + k0 + ac);
            *(uint2*)&Bu[r * AP + ac] = make_uint2(pk2(u.x, u.y), pk2(u.z, u.w));
        }
        __syncthreads();
        #pragma unroll
        for (int ks = 0; ks < 2; ++ks) {
            bf16x8 a0 = *(const bf16x8*)&As[(wv * 32 + lr) * AP + ks * 32 + lq * 8];
            bf16x8 a1 = *(const bf16x8*)&As[(wv * 32 + 16 + lr) * AP + ks * 32 + lq * 8];
            #pragma unroll
            for (int nj = 0; nj < 4; ++nj) {
                bf16x8 bg = *(const bf16x8*)&Bg[(nj * 16 + lr) * AP + ks * 32 + lq * 8];
                bf16x8 bu = *(const bf16x8*)&Bu[(nj * 16 + lr) * AP + ks * 32 + lq * 8];
                accg[0][nj] = __builtin_amdgcn_mfma_f32_16x16x32_bf16(a0, bg, accg[0][nj], 0, 0, 0);
                accg[1][nj] = __builtin_amdgcn_mfma_f32_16x16x32_bf16(a1, bg, accg[1][nj], 0, 0, 0);
                accu[0][nj] = __builtin_amdgcn_mfma_f32_16x16x32_bf16(a0, bu, accu[0][nj], 0, 0, 0);
                accu[1][nj] = __builtin_amdgcn_mfma_f32_16x16x32_bf16(a1, bu, accu[1][nj], 0, 0, 0);
            }
        }
        __syncthreads();
    }

    #pragma unroll
    for (int mi = 0; mi < 2; ++mi) {
        #pragma unroll
        for (int r = 0; r < 4; ++r) {
            int srow = wv * 32 + mi * 16 + lq * 4 + r;
            if (m0 + srow < cnt) {
                float w = wts[srow];
                unsigned short* ap = act + (size_t)(off + m0 + srow) * I_DIM + n0 + lr;
                #pragma unroll
                for (int nj = 0; nj < 4; ++nj) {
                    float g = accg[mi][nj][r];
                    float u = accu[mi][nj][r];
                    float a = w * (g / (1.f + __expf(-g))) * u;
                    ap[nj * 16] = bf1(a);
                }
            }
        }
    }
}

// ---------------- routed down proj: MFMA, atomic scatter-add ----------------
__global__ __launch_bounds__(256) void down_routed_mfma(
    const unsigned short* __restrict__ act, const float* __restrict__ Wd,
    const int* __restrict__ offs, const int* __restrict__ counts,
    const int* __restrict__ tok_list, float* __restrict__ out)
{
    const int e = blockIdx.z;
    const int cnt = counts[e];
    const int m0 = blockIdx.y * 128;
    if (m0 >= cnt) return;
    const int off = offs[e];
    const int n0 = blockIdx.x * 64;

    __shared__ unsigned short As[128 * AP];
    __shared__ unsigned short Bs[64 * AP];
    __shared__ int toks[128];

    const int tid = threadIdx.x;
    if (tid < 128) {
        int s = m0 + tid;
        toks[tid] = (s < cnt) ? tok_list[off + s] : 0;
    }
    __syncthreads();

    const int lane = tid & 63;
    const int wv = tid >> 6;
    const int lr = lane & 15;
    const int lq = lane >> 4;

    f32x4 acc[2][4];
    #pragma unroll
    for (int i = 0; i < 2; ++i)
        #pragma unroll
        for (int j = 0; j < 4; ++j)
            acc[i][j] = (f32x4){0.f, 0.f, 0.f, 0.f};

    const float* wdp = Wd + (size_t)e * H_DIM * I_DIM + (size_t)n0 * I_DIM;
    const unsigned short* ap0 = act + (size_t)(off + m0) * I_DIM;
    const int ar = tid >> 4;
    const int ac = (tid & 15) * 4;

    for (int k0 = 0; k0 < I_DIM; k0 += 64) {
        #pragma unroll
        for (int p = 0; p < 8; ++p) {
            int r = ar + p * 16;
            uint2 v = make_uint2(0u, 0u);
            if (m0 + r < cnt) v = *(const uint2*)(ap0 + (size_t)r * I_DIM + k0 + ac);
            *(uint2*)&As[r * AP + ac] = v;
        }
        #pragma unroll
        for (int p = 0; p < 4; ++p) {
            int r = ar + p * 16;
            float4 w4 = *(const float4*)(wdp + (size_t)r * I_DIM + k0 + ac);
            *(uint2*)&Bs[r * AP + ac] = make_uint2(pk2(w4.x, w4.y), pk2(w4.z, w4.w));
        }
        __syncthreads();
        #pragma unroll
        for (int ks = 0; ks < 2; ++ks) {
            bf16x8 a0 = *(const bf16x8*)&As[(wv * 32 + lr) * AP + ks * 32 + lq * 8];
            bf16x8 a1 = *(const bf16x8*)&As[(wv * 32 + 16 + lr) * AP + ks * 32 + lq * 8];
            #pragma unroll
            for (int nj = 0; nj < 4; ++nj) {
                bf16x8 b = *(const bf16x8*)&Bs[(nj * 16 + lr) * AP + ks * 32 + lq * 8];
                acc[0][nj] = __builtin_amdgcn_mfma_f32_16x16x32_bf16(a0, b, acc[0][nj], 0, 0, 0);
                acc[1][nj] = __builtin_amdgcn_mfma_f32_16x16x32_bf16(a1, b, acc[1][nj], 0, 0, 0);
            }
        }
        __syncthreads();
    }

    #pragma unroll
    for (int mi = 0; mi < 2; ++mi) {
        #pragma unroll
        for (int r = 0; r < 4; ++r) {
            int srow = wv * 32 + mi * 16 + lq * 4 + r;
            if (m0 + srow < cnt) {
                int t = toks[srow];
                float* op = out + (size_t)t * H_DIM + n0 + lr;
                #pragma unroll
                for (int nj = 0; nj < 4; ++nj)
                    atomicAdd(&op[nj * 16], acc[mi][nj][r]);
            }
        }
    }
}

// ---------------- shared expert gate/up: MFMA dense, bf16 sact out ----------------
__global__ __launch_bounds__(256) void gateup_shared_mfma(
    const float* __restrict__ x, const float* __restrict__ Sg, const float* __restrict__ Su,
    unsigned short* __restrict__ sact)
{
    const int m0 = blockIdx.y * 128;
    const int n0 = blockIdx.x * 64;

    __shared__ unsigned short As[128 * AP];
    __shared__ unsigned short Bg[64 * AP];
    __shared__ unsigned short Bu[64 * AP];

    const int tid = threadIdx.x;
    const int lane = tid & 63;
    const int wv = tid >> 6;
    const int lr = lane & 15;
    const int lq = lane >> 4;

    f32x4 accg[2][4], accu[2][4];
    #pragma unroll
    for (int i = 0; i < 2; ++i)
        #pragma unroll
        for (int j = 0; j < 4; ++j) {
            accg[i][j] = (f32x4){0.f, 0.f, 0.f, 0.f};
            accu[i][j] = (f32x4){0.f, 0.f, 0.f, 0.f};
        }

    const float* gp = Sg + (size_t)n0 * H_DIM;
    const float* up = Su + (size_t)n0 * H_DIM;
    const int ar = tid >> 4;
    const int ac = (tid & 15) * 4;

    for (int k0 = 0; k0 < H_DIM; k0 += 64) {
        #pragma unroll
        for (int p = 0; p < 8; ++p) {
            int r = ar + p * 16;
            float4 v = *(const float4*)(x + (size_t)(m0 + r) * H_DIM + k0 + ac);
            *(uint2*)&As[r * AP + ac] = make_uint2(pk2(v.x, v.y), pk2(v.z, v.w));
        }
        #pragma unroll
        for (int p = 0; p < 4; ++p) {
            int r = ar + p * 16;
            float4 g = *(const float4*)(gp + (size_t)r * H_DIM + k0 + ac);
            *(uint2*)&Bg[r * AP + ac] = make_uint2(pk2(g.x, g.y), pk2(g.z, g.w));
            float4 u = *(const float4*)(up + (size_t)r * H_DIM + k0 + ac);
            *(uint2*)&Bu[r * AP + ac] = make_uint2(pk2(u.x, u.y), pk2(u.z, u.w));
        }
        __syncthreads();
        #pragma unroll
        for (int ks = 0; ks < 2; ++ks) {
            bf16x8 a0 = *(const bf16x8*)&As[(wv * 32 + lr) * AP + ks * 32 + lq * 8];
            bf16x8 a1 = *(const bf16x8*)&As[(wv * 32 + 16 + lr) * AP + ks * 32 + lq * 8];
            #pragma unroll
            for (int nj = 0; nj < 4; ++nj) {
                bf16x8 bg = *(const bf16x8*)&Bg[(nj * 16 + lr) * AP + ks * 32 + lq * 8];
                bf16x8 bu = *(const bf16x8*)&Bu[(nj * 16 + lr) * AP + ks * 32 + lq * 8];
                accg[0][nj] = __builtin_amdgcn_mfma_f32_16x16x32_bf16(a0, bg, accg[0][nj], 0, 0, 0);
                accg[1][nj] = __builtin_amdgcn_mfma_f32_16x16x32_bf16(a1, bg, accg[1][nj], 0, 0, 0);
                accu[0][nj] = __builtin_amdgcn_mfma_f32_16x16x32_bf16(a0, bu, accu[0][nj], 0, 0, 0);
                accu[1][nj] = __builtin_amdgcn_mfma_f32_16x16x32_bf16(a1, bu, accu[1][nj], 0, 0, 0);
            }
        }
        __syncthreads();
    }

    #pragma unroll
    for (int mi = 0; mi < 2; ++mi) {
        #pragma unroll
        for (int r = 0; r < 4; ++r) {
            int trow = m0 + wv * 32 + mi * 16 + lq * 4 + r;
            unsigned short* sp = sact + (size_t)trow * SI_DIM + n0 + lr;
            #pragma unroll
            for (int nj = 0; nj < 4; ++nj) {
                float g = accg[mi][nj][r];
                float u = accu[mi][nj][r];
                float a = (g / (1.f + __expf(-g))) * u;
                sp[nj * 16] = bf1(a);
            }
        }
    }
}

// ---------------- shared expert down proj: MFMA dense, writes out ----------------
__global__ __launch_bounds__(256) void down_shared_mfma(
    const unsigned short* __restrict__ sact, const float* __restrict__ Sd,
    float* __restrict__ out)
{
    const int m0 = blockIdx.y * 128;
    const int n0 = blockIdx.x * 64;

    __shared__ unsigned short As[128 * AP];
    __shared__ unsigned short Bs[64 * AP];

    const int tid = threadIdx.x;
    const int lane = tid & 63;
    const int wv = tid >> 6;
    const int lr = lane & 15;
    const int lq = lane >> 4;

    f32x4 acc[2][4];
    #pragma unroll
    for (int i = 0; i < 2; ++i)
        #pragma unroll
        for (int j = 0; j < 4; ++j)
            acc[i][j] = (f32x4){0.f, 0.f, 0.f, 0.f};

    const float* wp = Sd + (size_t)n0 * SI_DIM;
    const int ar = tid >> 4;
    const int ac = (tid & 15) * 4;

    for (int k0 = 0; k0 < SI_DIM; k0 += 64) {
        #pragma unroll
        for (int p = 0; p < 8; ++p) {
            int r = ar + p * 16;
            uint2 v = *(const uint2*)(sact + (size_t)(m0 + r) * SI_DIM + k0 + ac);
            *(uint2*)&As[r * AP + ac] = v;
        }
        #pragma unroll
        for (int p = 0; p < 4; ++p) {
            int r = ar + p * 16;
            float4 w4 = *(const float4*)(wp + (size_t)r * SI_DIM + k0 + ac);
            *(uint2*)&Bs[r * AP + ac] = make_uint2(pk2(w4.x, w4.y), pk2(w4.z, w4.w));
        }
        __syncthreads();
        #pragma unroll
        for (int ks = 0; ks < 2; ++ks) {
            bf16x8 a0 = *(const bf16x8*)&As[(wv * 32 + lr) * AP + ks * 32 + lq * 8];
            bf16x8 a1 = *(const bf16x8*)&As[(wv * 32 + 16 + lr) * AP + ks * 32 + lq * 8];
            #pragma unroll
            for (int nj = 0; nj < 4; ++nj) {
                bf16x8 b = *(const bf16x8*)&Bs[(nj * 16 + lr) * AP + ks * 32 + lq * 8];
                acc[0][nj] = __builtin_amdgcn_mfma_f32_16x16x32_bf16(a0, b, acc[0][nj], 0, 0, 0);
                acc[1][nj] = __builtin_amdgcn_mfma_f32_16x16x32_bf16(a1, b, acc[1][nj], 0, 0, 0);
            }
        }
        __syncthreads();
    }

    #pragma unroll
    for (int mi = 0; mi < 2; ++mi) {
        #pragma unroll
        for (int r = 0; r < 4; ++r) {
            int trow = m0 + wv * 32 + mi * 16 + lq * 4 + r;
            float* op = out + (size_t)trow * H_DIM + n0 + lr;
            #pragma unroll
            for (int nj = 0; nj < 4; ++nj)
                op[nj * 16] = acc[mi][nj][r];
        }
    }
}

// ---------------- launch ----------------
extern "C" void kernel_launch(void* const* d_in, const int* in_sizes, int n_in,
                              void* d_out, int out_size, void* d_ws, size_t ws_size,
                              hipStream_t stream)
{
    const float* x  = (const float*)d_in[0];
    const float* gw = (const float*)d_in[1];
    const float* gb = (const float*)d_in[2];
    const float* Wg = (const float*)d_in[3];
    const float* Wu = (const float*)d_in[4];
    const float* Wd = (const float*)d_in[5];
    const float* Sg = (const float*)d_in[6];
    const float* Su = (const float*)d_in[7];
    const float* Sd = (const float*)d_in[8];
    float* out = (float*)d_out;

    // workspace layout: bf16 buffers first (16B-aligned), then int/float lists
    unsigned short* act  = (unsigned short*)d_ws;                 // 8192*704 bf16
    unsigned short* sact = act + (size_t)NSLOT * I_DIM;           // 1024*1408 bf16
    int* counts   = (int*)(sact + (size_t)T_TOK * SI_DIM);        // 64
    int* fillc    = counts + 64;                                  // 64
    int* offs     = fillc + 64;                                   // 64
    int* tk_idx   = offs + 64;                                    // 8192
    float* tk_w   = (float*)(tk_idx + NSLOT);                     // 8192
    int* tok_list = (int*)(tk_w + NSLOT);                         // 8192
    float* w_list = (float*)(tok_list + NSLOT);                   // 8192

    zero_kernel<<<1, 64, 0, stream>>>(counts, fillc);
    route_kernel<<<T_TOK, 64, 0, stream>>>(x, gw, gb, counts, tk_idx, tk_w);
    scan_kernel<<<1, 64, 0, stream>>>(counts, offs);
    fill_kernel<<<4, 256, 0, stream>>>(tk_idx, tk_w, offs, fillc, tok_list, w_list);

    gateup_routed_mfma<<<dim3(11, 8, 64), 256, 0, stream>>>(x, Wg, Wu, offs, counts, tok_list, w_list, act);
    gateup_shared_mfma<<<dim3(22, 8, 1), 256, 0, stream>>>(x, Sg, Su, sact);
    down_shared_mfma<<<dim3(16, 8, 1), 256, 0, stream>>>(sact, Sd, out);
    down_routed_mfma<<<dim3(16, 8, 64), 256, 0, stream>>>(act, Wd, offs, counts, tok_list, out);
}